// Round 9
// baseline (99.730 us; speedup 1.0000x reference)
//
#include <hip/hip_runtime.h>
#include <hip/hip_bf16.h>
#include <stdint.h>

typedef __hip_bfloat16 bf16;
typedef float f32x4 __attribute__((ext_vector_type(4)));
typedef short bf16x8 __attribute__((ext_vector_type(8)));

#define NB 16384
#define NA 16
#define ND 512
#define NH 512
#define TR 64  // rows/tile: 32 tiles/XCD-pair over 64 slots (2 blocks/CU) -> no tail

// workspace layout (bytes)
#define W1S_OFF 0u
#define W2S_OFF 8388608u
#define PERM_OFF 16777216u
#define META_OFF 16842752u
// meta ints: [0..15]=cnt, [16..31]=off

__device__ __forceinline__ unsigned short f2b(float x) {
  unsigned int b = __float_as_uint(x);
  return (unsigned short)((b + 0x7FFFu + ((b >> 16) & 1u)) >> 16);  // RNE
}

// ---------------- prep: W transpose+cast (blocks 0..2047) + meta (block 2048) -------------
// Weight layout per action: blob[(h>>4)*16 + (k>>5)] of 1KB; byte =
// ((k>>3)&3)*256 + (h&15)*16 + (k&7)*2.  A wave's MFMA A-fragment = 1KB contiguous.
// Meta: zero-atomic ballot scheme -> deterministic perm (original index order).
__global__ __launch_bounds__(256) void k_prep(const float* __restrict__ W1,
                                              const float* __restrict__ W2,
                                              bf16* __restrict__ W1s,
                                              bf16* __restrict__ W2s,
                                              const int* __restrict__ act,
                                              int* __restrict__ meta,
                                              int* __restrict__ perm) {
  if (blockIdx.x == 2048) {
    __shared__ unsigned short pfx[64][4][16];  // per (iter, wave, action) count -> prefix
    __shared__ int cnt[16], off[16];
    int tid = threadIdx.x;
    int wv = tid >> 6, lane = tid & 63;
    unsigned long long below = (lane == 0) ? 0ull : (~0ull >> (64 - lane));
    // zero pfx (4096 u16 = 2048 u32)
    for (int i = tid; i < 2048; i += 256) ((unsigned int*)pfx)[i] = 0u;
    __syncthreads();
    // phase 1: ballot counts, leader writes (no atomics: one group per action per (i,wv))
    for (int i = 0; i < 64; ++i) {
      int a = act[tid + (i << 8)] & 15;
      unsigned long long m = ~0ull;
#pragma unroll
      for (int b = 0; b < 4; ++b) {
        unsigned long long bal = __ballot((a >> b) & 1);
        m &= ((a >> b) & 1) ? bal : ~bal;
      }
      if (lane == (__ffsll((unsigned long long)m) - 1))
        pfx[i][wv][a] = (unsigned short)__popcll(m);
    }
    __syncthreads();
    // phase 2: exclusive prefix over (i,wv) per action; 16 threads in parallel
    if (tid < 16) {
      int run = 0;
      for (int i = 0; i < 64; ++i)
#pragma unroll
        for (int v = 0; v < 4; ++v) {
          int t = pfx[i][v][tid];
          pfx[i][v][tid] = (unsigned short)run;
          run += t;
        }
      cnt[tid] = run;
    }
    __syncthreads();
    if (tid == 0) {
      int o = 0;
      for (int aa = 0; aa < 16; ++aa) {
        off[aa] = o;
        o += cnt[aa];
      }
    }
    __syncthreads();
    // phase 4: deterministic scatter, no atomics
    for (int i = 0; i < 64; ++i) {
      int idx = tid + (i << 8);
      int a = act[idx] & 15;
      unsigned long long m = ~0ull;
#pragma unroll
      for (int b = 0; b < 4; ++b) {
        unsigned long long bal = __ballot((a >> b) & 1);
        m &= ((a >> b) & 1) ? bal : ~bal;
      }
      int rank = (int)__popcll(m & below);
      perm[off[a] + (int)pfx[i][wv][a] + rank] = idx;
    }
    if (tid < 16) {
      meta[tid] = cnt[tid];
      meta[16 + tid] = off[tid];
    }
    return;
  }
  __shared__ float tile[64][65];
  int blk = blockIdx.x;          // 0..2047
  int m = blk >> 6;              // matrix 0..31
  int tl = blk & 63;
  int td = tl >> 3, th = tl & 7;
  const float* src = (m < NA) ? (W1 + (size_t)m * (ND * NH)) : (W2 + (size_t)(m - NA) * (ND * NH));
  char* dstb = (m < NA) ? ((char*)W1s + ((size_t)m << 19)) : ((char*)W2s + ((size_t)(m - NA) << 19));
  int t = threadIdx.x;
  int r = t >> 2, c0 = (t & 3) << 4;
  const float* sp = src + (size_t)(td * 64 + r) * NH + th * 64 + c0;
  float4 v0 = ((const float4*)sp)[0];
  float4 v1 = ((const float4*)sp)[1];
  float4 v2 = ((const float4*)sp)[2];
  float4 v3 = ((const float4*)sp)[3];
  float* tr = &tile[r][c0];
  tr[0] = v0.x; tr[1] = v0.y; tr[2] = v0.z; tr[3] = v0.w;
  tr[4] = v1.x; tr[5] = v1.y; tr[6] = v1.z; tr[7] = v1.w;
  tr[8] = v2.x; tr[9] = v2.y; tr[10] = v2.z; tr[11] = v2.w;
  tr[12] = v3.x; tr[13] = v3.y; tr[14] = v3.z; tr[15] = v3.w;
  __syncthreads();
  int hloc = t >> 2, dc = (t & 3) << 4;
  int h = th * 64 + hloc;
  int K0 = td * 64 + dc;
  union { unsigned short us[16]; uint4 q[2]; } u;
#pragma unroll
  for (int i = 0; i < 16; ++i) u.us[i] = f2b(tile[dc + i][hloc]);
  size_t ab = (size_t)((h >> 4) * 16 + (K0 >> 5)) * 1024 + (size_t)(h & 15) * 16;
  *(uint4*)(dstb + ab + (((K0 >> 3) & 3) << 8)) = u.q[0];
  *(uint4*)(dstb + ab + ((((K0 >> 3) + 1) & 3) << 8)) = u.q[1];
}

// ---------------- fused grouped MLP ----------------
// XCD x (bid&7) owns actions 2x,2x+1 (2MB L2 set). TR=64, LDS 67.6KB -> 2 blocks/CU,
// 16 waves/CU. Block: 64-row tile, 8 waves; wave w owns h [w*64,+64) x 64 cols.
// Weights: depth-4 register ping-pong A[4][4], fragment-tiled 1KB coalesced loads.
__global__ __launch_bounds__(512, 4) void k_main(
    const float* __restrict__ state, const float* __restrict__ b1,
    const float* __restrict__ b2, const float* __restrict__ W3,
    const float* __restrict__ b3, const bf16* __restrict__ W1s,
    const bf16* __restrict__ W2s, const int* __restrict__ perm,
    const int* __restrict__ meta, float* __restrict__ out) {
  extern __shared__ char smem[];
  char* Xs = smem;
  float* outbuf = (float*)(smem + 65536);

  int bid = blockIdx.x;
  int xcd = bid & 7, slot = bid >> 3;
  int a0 = xcd << 1;
  int n0 = meta[a0], n1 = meta[a0 + 1];
  int nt0 = (n0 + TR - 1) / TR, nt1 = (n1 + TR - 1) / TR;
  int a, t;
  if (slot < nt0) {
    a = a0; t = slot;
  } else if (slot < nt0 + nt1) {
    a = a0 + 1; t = slot - nt0;
  } else {
    return;
  }
  int rowbase = meta[16 + a] + t * TR;
  int nrows = meta[a] - t * TR;
  nrows = nrows > TR ? TR : nrows;

  int tid = threadIdx.x;
  int lane = tid & 63;
  int w = tid >> 6;
  int l15 = lane & 15, l4 = lane >> 4;

  bf16x8 A[4][4];  // [slot][hf] depth-4 weight pipeline
  bf16x8 Bc[4], Bn[4];
  const char* Wl = (const char*)W1s + ((size_t)a << 19) + (w << 16) + (lane << 4);
#pragma unroll
  for (int s = 0; s < 4; ++s)
#pragma unroll
    for (int hf = 0; hf < 4; ++hf)
      A[s][hf] = *(const bf16x8*)(Wl + hf * 16384 + s * 1024);

  // ---- stage X tile -> LDS bf16, swizzle byte ^= (row&7)<<4 ----
  {
#pragma unroll
    for (int it = 0; it < 16; ++it) {
      int c = tid + (it << 9);
      int row = c >> 7, chunk = c & 127;
      int gr = (row < nrows) ? perm[rowbase + row] : -1;
      float4 v = make_float4(0.f, 0.f, 0.f, 0.f);
      if (gr >= 0) v = *(const float4*)(state + (size_t)gr * ND + (chunk << 2));
      uint2 pk;
      pk.x = (unsigned)f2b(v.x) | ((unsigned)f2b(v.y) << 16);
      pk.y = (unsigned)f2b(v.z) | ((unsigned)f2b(v.w) << 16);
      *(uint2*)(Xs + row * 1024 + ((chunk << 3) ^ ((row & 7) << 4))) = pk;
    }
  }
  __syncthreads();

  uint2 h1p[16];

  // ---- layer 1: h1 = relu(X @ W1 + b1), [h][b], h1 kept in registers ----
  {
    f32x4 acc[4][4] = {};
#pragma unroll
    for (int bf = 0; bf < 4; ++bf) {
      int b = (bf << 4) + l15;
      Bc[bf] = *(const bf16x8*)(Xs + b * 1024 + ((l4 << 4) ^ ((b & 7) << 4)));
    }
#pragma unroll
    for (int ks = 0; ks < 16; ++ks) {
      if (ks < 15) {
#pragma unroll
        for (int bf = 0; bf < 4; ++bf) {
          int b = (bf << 4) + l15;
          Bn[bf] = *(const bf16x8*)(Xs + b * 1024 + ((((ks + 1) << 6) + (l4 << 4)) ^ ((b & 7) << 4)));
        }
      }
#pragma unroll
      for (int hf = 0; hf < 4; ++hf)
#pragma unroll
        for (int bf = 0; bf < 4; ++bf)
          acc[hf][bf] = __builtin_amdgcn_mfma_f32_16x16x32_bf16(A[ks & 3][hf], Bc[bf], acc[hf][bf], 0, 0, 0);
      if (ks < 12) {
#pragma unroll
        for (int hf = 0; hf < 4; ++hf)
          A[ks & 3][hf] = *(const bf16x8*)(Wl + hf * 16384 + (ks + 4) * 1024);
      }
#pragma unroll
      for (int bf = 0; bf < 4; ++bf) Bc[bf] = Bn[bf];
    }
    // issue layer-2 A preloads; latency hides under epilogue + barrier
    const char* Wl2 = (const char*)W2s + ((size_t)a << 19) + (w << 16) + (lane << 4);
#pragma unroll
    for (int s = 0; s < 4; ++s)
#pragma unroll
      for (int hf = 0; hf < 4; ++hf)
        A[s][hf] = *(const bf16x8*)(Wl2 + hf * 16384 + s * 1024);
    // epilogue: bias + relu + pack bf16 into registers
#pragma unroll
    for (int hf = 0; hf < 4; ++hf) {
      int hb = (w << 6) + (hf << 4) + (l4 << 2);
      float4 bias = *(const float4*)(b1 + (a << 9) + hb);
#pragma unroll
      for (int bf = 0; bf < 4; ++bf) {
        float x0 = fmaxf(acc[hf][bf][0] + bias.x, 0.f);
        float x1 = fmaxf(acc[hf][bf][1] + bias.y, 0.f);
        float x2 = fmaxf(acc[hf][bf][2] + bias.z, 0.f);
        float x3 = fmaxf(acc[hf][bf][3] + bias.w, 0.f);
        h1p[hf * 4 + bf].x = (unsigned)f2b(x0) | ((unsigned)f2b(x1) << 16);
        h1p[hf * 4 + bf].y = (unsigned)f2b(x2) | ((unsigned)f2b(x3) << 16);
      }
    }
  }
  __syncthreads();  // all waves done reading X
#pragma unroll
  for (int hf = 0; hf < 4; ++hf) {
    int hb2 = ((w << 6) + (hf << 4) + (l4 << 2)) << 1;
#pragma unroll
    for (int bf = 0; bf < 4; ++bf) {
      int b = (bf << 4) + l15;
      *(uint2*)(Xs + b * 1024 + (hb2 ^ ((b & 7) << 4))) = h1p[hf * 4 + bf];
    }
  }
  __syncthreads();

  // ---- layer 2 + fused layer 3: out = relu(h1 @ W2 + b2) . W3 + b3 ----
  {
    f32x4 acc[4][4] = {};
    const char* Wl2 = (const char*)W2s + ((size_t)a << 19) + (w << 16) + (lane << 4);
#pragma unroll
    for (int bf = 0; bf < 4; ++bf) {
      int b = (bf << 4) + l15;
      Bc[bf] = *(const bf16x8*)(Xs + b * 1024 + ((l4 << 4) ^ ((b & 7) << 4)));
    }
#pragma unroll
    for (int ks = 0; ks < 16; ++ks) {
      if (ks < 15) {
#pragma unroll
        for (int bf = 0; bf < 4; ++bf) {
          int b = (bf << 4) + l15;
          Bn[bf] = *(const bf16x8*)(Xs + b * 1024 + ((((ks + 1) << 6) + (l4 << 4)) ^ ((b & 7) << 4)));
        }
      }
#pragma unroll
      for (int hf = 0; hf < 4; ++hf)
#pragma unroll
        for (int bf = 0; bf < 4; ++bf)
          acc[hf][bf] = __builtin_amdgcn_mfma_f32_16x16x32_bf16(A[ks & 3][hf], Bc[bf], acc[hf][bf], 0, 0, 0);
      if (ks < 12) {
#pragma unroll
        for (int hf = 0; hf < 4; ++hf)
          A[ks & 3][hf] = *(const bf16x8*)(Wl2 + hf * 16384 + (ks + 4) * 1024);
      }
#pragma unroll
      for (int bf = 0; bf < 4; ++bf) Bc[bf] = Bn[bf];
    }
    float part[4] = {0.f, 0.f, 0.f, 0.f};
#pragma unroll
    for (int hf = 0; hf < 4; ++hf) {
      int hb = (w << 6) + (hf << 4) + (l4 << 2);
      float4 bias = *(const float4*)(b2 + (a << 9) + hb);
      float4 w3v = *(const float4*)(W3 + (a << 9) + hb);
#pragma unroll
      for (int bf = 0; bf < 4; ++bf) {
        part[bf] += fmaxf(acc[hf][bf][0] + bias.x, 0.f) * w3v.x +
                    fmaxf(acc[hf][bf][1] + bias.y, 0.f) * w3v.y +
                    fmaxf(acc[hf][bf][2] + bias.z, 0.f) * w3v.z +
                    fmaxf(acc[hf][bf][3] + bias.w, 0.f) * w3v.w;
      }
    }
#pragma unroll
    for (int bf = 0; bf < 4; ++bf) {
      float p = part[bf];
      p += __shfl_xor(p, 16);
      p += __shfl_xor(p, 32);
      if (l4 == 0) outbuf[(w << 6) + (bf << 4) + l15] = p;
    }
  }
  __syncthreads();
  if (tid < nrows) {
    float s = b3[a];
#pragma unroll
    for (int ww = 0; ww < 8; ++ww) s += outbuf[(ww << 6) + tid];
    out[perm[rowbase + tid]] = s;
  }
}

extern "C" void kernel_launch(void* const* d_in, const int* in_sizes, int n_in,
                              void* d_out, int out_size, void* d_ws, size_t ws_size,
                              hipStream_t stream) {
  const float* state = (const float*)d_in[0];
  const float* W1 = (const float*)d_in[1];
  const float* b1 = (const float*)d_in[2];
  const float* W2 = (const float*)d_in[3];
  const float* b2 = (const float*)d_in[4];
  const float* W3 = (const float*)d_in[5];
  const float* b3 = (const float*)d_in[6];
  const int* actions = (const int*)d_in[7];
  float* out = (float*)d_out;
  char* ws = (char*)d_ws;
  bf16* W1s = (bf16*)(ws + W1S_OFF);
  bf16* W2s = (bf16*)(ws + W2S_OFF);
  int* perm = (int*)(ws + PERM_OFF);
  int* meta = (int*)(ws + META_OFF);

  k_prep<<<2049, 256, 0, stream>>>(W1, W2, W1s, W2s, actions, meta, perm);
  hipFuncSetAttribute((const void*)k_main, hipFuncAttributeMaxDynamicSharedMemorySize, 67584);
  k_main<<<512, 512, 67584, stream>>>(state, b1, b2, W3, b3, W1s, W2s, perm, meta, out);
}